// Round 9
// baseline (898.025 us; speedup 1.0000x reference)
//
#include <hip/hip_runtime.h>

#define H 128
#define LN_EPS 1e-5f

typedef _Float16 half8 __attribute__((ext_vector_type(8)));
typedef float floatx4 __attribute__((ext_vector_type(4)));

__device__ __forceinline__ float silu_f(float x) { return x / (1.0f + __expf(-x)); }

// ---------------------------------------------------------------------------
// fp32 -> fp16 converters (one-time per launch)
// ---------------------------------------------------------------------------
__global__ void cvt_h16(const float* __restrict__ src, _Float16* __restrict__ dst,
                        int total8)
{
    int i = blockIdx.x * blockDim.x + threadIdx.x;
    if (i >= total8) return;
    const float4* p = (const float4*)(src + i * 8);
    float4 a = p[0], b = p[1];
    half8 o;
    o[0] = (_Float16)a.x; o[1] = (_Float16)a.y; o[2] = (_Float16)a.z; o[3] = (_Float16)a.w;
    o[4] = (_Float16)b.x; o[5] = (_Float16)b.y; o[6] = (_Float16)b.z; o[7] = (_Float16)b.w;
    *(half8*)(dst + i * 8) = o;
}

// W [K][128] fp32 -> WT [128][Kpad] fp16 (zero-padded K..Kpad)
__global__ void cvt_wT(const float* __restrict__ W, _Float16* __restrict__ WT,
                       int K, int Kpad)
{
    int i = blockIdx.x * blockDim.x + threadIdx.x;
    if (i >= 128 * Kpad) return;
    int n = i / Kpad, k = i - n * Kpad;
    WT[i] = (k < K) ? (_Float16)W[k * H + n] : (_Float16)0.0f;
}

// ---------------------------------------------------------------------------
// Full counting sort by dst (N bins).  cnt/base/cursor are N-sized arrays.
// ---------------------------------------------------------------------------
__global__ void hist2_kernel(const int* __restrict__ edst, int E,
                             int* __restrict__ cnt)
{
    for (int e = blockIdx.x * blockDim.x + threadIdx.x; e < E;
         e += gridDim.x * blockDim.x)
        atomicAdd(&cnt[edst[e]], 1);
}

__global__ void __launch_bounds__(1024)
scan2_kernel(const int* __restrict__ cnt, int* __restrict__ base,
             int* __restrict__ cursor, int N)
{
    __shared__ int part[1024];
    const int chunk = (N + 1023) >> 10;
    const int lo = threadIdx.x * chunk;
    const int hi = min(lo + chunk, N);
    int s = 0;
    for (int i = lo; i < hi; i++) s += cnt[i];
    part[threadIdx.x] = s;
    __syncthreads();
    if (threadIdx.x == 0) {
        int r = 0;
        for (int i = 0; i < 1024; i++) { int c = part[i]; part[i] = r; r += c; }
    }
    __syncthreads();
    int run = part[threadIdx.x];
    for (int i = lo; i < hi; i++) {
        base[i] = run; cursor[i] = run;
        run += cnt[i];
    }
}

__global__ void binfo_kernel(const int* __restrict__ base, int N, int bsz, int E,
                             int* __restrict__ binfo)
{
    int b = threadIdx.x;
    if (b < 8) {
        int lo = min(b * bsz, N);
        int hi = min((b + 1) * bsz, N);
        int blo = (lo >= N) ? E : base[lo];
        int bhi = (hi >= N) ? E : base[hi];
        binfo[8 + b] = blo;
        binfo[b]     = bhi - blo;
    }
}

__global__ void scatter2_kernel(const int* __restrict__ edst, int E,
                                int* __restrict__ cursor, int* __restrict__ perm)
{
    for (int e = blockIdx.x * blockDim.x + threadIdx.x; e < E;
         e += gridDim.x * blockDim.x) {
        int p = atomicAdd(&cursor[edst[e]], 1);
        perm[p] = e;
    }
}

// ---------------------------------------------------------------------------
// Edge kernel: 64-edge tiles of dst-SORTED edges.  Full [64][320] fp16 A-tile
// staged in one burst; barrier-light MFMA loops with B streamed from fp16
// weight tables (lockstep via raw s_barrier for L1 reuse); epilogue does a
// run-length reduction over sorted dsts -> ~1 atomic per (run, col).
// ---------------------------------------------------------------------------
__global__ void __launch_bounds__(256, 3)
edge_mfma(const _Float16* __restrict__ h16,
          const int* __restrict__ perm, const int* __restrict__ binfo,
          const int* __restrict__ esrc, const int* __restrict__ edst,
          const int* __restrict__ erel, const int* __restrict__ ncol,
          const int* __restrict__ nrole,
          const float* __restrict__ rel_emb, const float* __restrict__ role_emb,
          const float* __restrict__ col_emb,
          const _Float16* __restrict__ w1t,   // [128][320]
          const float* __restrict__ eb1,
          const _Float16* __restrict__ w2t,   // [128][128]
          const float* __restrict__ eb2,
          float* __restrict__ agg)
{
    // union: A-tile [64][320]@stride328 fp16 / sY [64][128]@136 fp16
    //        / message tile M [64][128]@132 fp32
    __shared__ __align__(16) _Float16 sAY[64 * 328];
    __shared__ int sSrc[64], sDst[64], sRel[64], sRS[64], sRD[64], sCS[64], sCD[64];
    __shared__ float sRelE[128], sRoleE[48], sColE[24];

    const int tid  = threadIdx.x;
    const int lane = tid & 63;
    const int wv   = tid >> 6;
    const int lm   = lane & 15;
    const int lh   = lane >> 4;

    if (tid < 128) sRelE[tid] = rel_emb[tid];
    if (tid < 48)  sRoleE[tid] = role_emb[tid];
    if (tid < 24)  sColE[tid] = col_emb[tid];

    const int bucket = blockIdx.x;
    const int bcount = binfo[bucket];
    const int bbase  = binfo[8 + bucket];

    const int ae  = tid >> 2;          // staged edge row
    const int akq = (tid & 3) * 8;     // k-quad base within 32-slice

    for (int t = blockIdx.y; t * 64 < bcount; t += gridDim.y)
    {
        __syncthreads();   // previous tile fully consumed

        if (tid < 64) {
            int idx   = t * 64 + tid;
            int valid = idx < bcount;
            int e = valid ? perm[bbase + idx] : perm[bbase];
            int s = esrc[e], d = edst[e], r = erel[e];
            sSrc[tid] = s; sRel[tid] = r;
            sRS[tid]  = nrole[s]; sRD[tid] = nrole[d];
            sCS[tid]  = ncol[s];  sCD[tid] = ncol[d];
            sDst[tid] = valid ? d : -1;
        }
        __syncthreads();

        // ---- stage full A-tile: 8 global half8 gathers in flight + 2 emb ----
        {
            const int src = sSrc[ae];
            int dd = sDst[ae]; if (dd < 0) dd = src;
            const _Float16* sp = &h16[src * H + akq];
            const _Float16* dp = &h16[dd  * H + akq];
            half8 t0 = *(const half8*)(sp);
            half8 t1 = *(const half8*)(sp + 32);
            half8 t2 = *(const half8*)(sp + 64);
            half8 t3 = *(const half8*)(sp + 96);
            half8 t4 = *(const half8*)(dp);
            half8 t5 = *(const half8*)(dp + 32);
            half8 t6 = *(const half8*)(dp + 64);
            half8 t7 = *(const half8*)(dp + 96);

            half8 t8, t9;
            {   // k = 256+akq
                const float* p;
                if (akq < 16)      p = &sRelE[sRel[ae] * 16 + akq];
                else if (akq < 24) p = &sRoleE[sRS[ae] * 8];
                else               p = &sRoleE[sRD[ae] * 8];
                #pragma unroll
                for (int j = 0; j < 8; j++) t8[j] = (_Float16)p[j];
            }
            {   // k = 288+akq
                if (akq == 0) {
                    const float* p = &sColE[sCS[ae] * 8];
                    #pragma unroll
                    for (int j = 0; j < 8; j++) t9[j] = (_Float16)p[j];
                } else if (akq == 8) {
                    const float* p = &sColE[sCD[ae] * 8];
                    #pragma unroll
                    for (int j = 0; j < 8; j++) t9[j] = (_Float16)p[j];
                } else {
                    #pragma unroll
                    for (int j = 0; j < 8; j++) t9[j] = (_Float16)0.0f;
                }
            }
            _Float16* w = &sAY[ae * 328 + akq];
            *(half8*)(w + 0 * 32) = t0;
            *(half8*)(w + 1 * 32) = t1;
            *(half8*)(w + 2 * 32) = t2;
            *(half8*)(w + 3 * 32) = t3;
            *(half8*)(w + 4 * 32) = t4;
            *(half8*)(w + 5 * 32) = t5;
            *(half8*)(w + 6 * 32) = t6;
            *(half8*)(w + 7 * 32) = t7;
            *(half8*)(w + 8 * 32) = t8;
            *(half8*)(w + 9 * 32) = t9;
        }

        floatx4 acc[8];
        #pragma unroll
        for (int f = 0; f < 8; f++) acc[f] = (floatx4){0.f, 0.f, 0.f, 0.f};

        __syncthreads();

        // ---- MLP1: K = 320, 10 steps; raw s_barrier keeps waves lockstep so
        //      all 4 waves reuse the same 8KB w1t slice in L1 ----
        #pragma unroll 2
        for (int s = 0; s < 10; s++) {
            __builtin_amdgcn_s_barrier();
            half8 af = *(const half8*)&sAY[(wv * 16 + lm) * 328 + s * 32 + lh * 8];
            const int kb = s * 32 + lh * 8;
            #pragma unroll
            for (int f = 0; f < 8; f++) {
                half8 bf = *(const half8*)&w1t[(f * 16 + lm) * 320 + kb];
                acc[f] = __builtin_amdgcn_mfma_f32_16x16x32_f16(af, bf, acc[f], 0, 0, 0);
            }
        }

        __syncthreads();   // all sA reads done before sY overwrite

        // y = silu(acc + eb1) -> sY (stride 136; C layout col=lm, row=lh*4+v)
        #pragma unroll
        for (int f = 0; f < 8; f++) {
            const int col = f * 16 + lm;
            const float b1 = eb1[col];
            #pragma unroll
            for (int v = 0; v < 4; v++) {
                const int row = wv * 16 + lh * 4 + v;
                sAY[row * 136 + col] = (_Float16)silu_f(acc[f][v] + b1);
            }
        }

        floatx4 acc2[8];
        #pragma unroll
        for (int f = 0; f < 8; f++) acc2[f] = (floatx4){0.f, 0.f, 0.f, 0.f};

        __syncthreads();

        // ---- MLP2: K = 128, 4 steps ----
        #pragma unroll
        for (int s2 = 0; s2 < 4; s2++) {
            __builtin_amdgcn_s_barrier();
            half8 af = *(const half8*)&sAY[(wv * 16 + lm) * 136 + s2 * 32 + lh * 8];
            const int kb = s2 * 32 + lh * 8;
            #pragma unroll
            for (int f = 0; f < 8; f++) {
                half8 bf = *(const half8*)&w2t[(f * 16 + lm) * 128 + kb];
                acc2[f] = __builtin_amdgcn_mfma_f32_16x16x32_f16(af, bf, acc2[f], 0, 0, 0);
            }
        }

        __syncthreads();   // every wave done reading its sY rows

        // messages (fp32, silu applied) -> M [64][132] reusing sAY
        float* M = (float*)sAY;
        #pragma unroll
        for (int f = 0; f < 8; f++) {
            const int col = f * 16 + lm;
            const float b2 = eb2[col];
            #pragma unroll
            for (int v = 0; v < 4; v++) {
                const int row = wv * 16 + lh * 4 + v;
                M[row * 132 + col] = silu_f(acc2[f][v] + b2);
            }
        }

        __syncthreads();

        // ---- run-length reduction over sorted dsts: 1 atomic per run/col ----
        {
            const int c   = tid & 127;          // column
            const int r0r = (tid >> 7) * 32;    // rows 0-31 or 32-63
            float a = 0.0f;
            int cur = -1;
            for (int r = r0r; r < r0r + 32; r++) {
                int d = sDst[r];                 // wave-uniform
                if (d != cur) {
                    if (cur >= 0) unsafeAtomicAdd(&agg[cur * H + c], a);
                    a = 0.0f; cur = d;
                }
                if (d >= 0) a += M[r * 132 + c];
            }
            if (cur >= 0) unsafeAtomicAdd(&agg[cur * H + c], a);
        }
    }
}

// ---------------------------------------------------------------------------
// Node kernel (fp16 MFMA): unchanged (not the bottleneck).
// ---------------------------------------------------------------------------
__global__ void __launch_bounds__(256)
node_mfma(const float* __restrict__ h, const float* __restrict__ agg,
          const int* __restrict__ ncol, const int* __restrict__ nrole,
          const float* __restrict__ role_emb, const float* __restrict__ col_emb,
          const float* __restrict__ nW1, const float* __restrict__ nb1,
          const float* __restrict__ nW2, const float* __restrict__ nb2,
          const float* __restrict__ ln_g, const float* __restrict__ ln_b,
          float* __restrict__ out, int N)
{
    __shared__ _Float16 sA[64 * 40];
    __shared__ _Float16 sB[128 * 40];
    __shared__ _Float16 sY[64 * 136];
    __shared__ int sRole[64], sCol[64];
    __shared__ float sRoleE[48], sColE[24];

    const int tid  = threadIdx.x;
    const int lane = tid & 63;
    const int wv   = tid >> 6;
    const int lm   = lane & 15;
    const int lh   = lane >> 4;
    const int n0   = blockIdx.x * 64;

    if (tid < 48) sRoleE[tid] = role_emb[tid];
    if (tid < 24) sColE[tid] = col_emb[tid];
    if (tid < 64) {
        int n = n0 + tid; if (n >= N) n = N - 1;
        sRole[tid] = nrole[n];
        sCol[tid]  = ncol[n];
    }

    floatx4 acc[8];
    #pragma unroll
    for (int f = 0; f < 8; f++) acc[f] = (floatx4){0.f, 0.f, 0.f, 0.f};

    __syncthreads();

    for (int s = 0; s < 9; s++) {
        const int k0 = s * 32;
        {
            const int r  = tid >> 2;
            const int kq = (tid & 3) * 8;
            const int k  = k0 + kq;
            int n = n0 + r; if (n >= N) n = N - 1;
            float v[8];
            if (k < 128) {
                const float4* p = (const float4*)&h[n * H + k];
                float4 a = p[0], b = p[1];
                v[0]=a.x; v[1]=a.y; v[2]=a.z; v[3]=a.w;
                v[4]=b.x; v[5]=b.y; v[6]=b.z; v[7]=b.w;
            } else if (k < 256) {
                const float4* p = (const float4*)&agg[n * H + (k - 128)];
                float4 a = p[0], b = p[1];
                v[0]=a.x; v[1]=a.y; v[2]=a.z; v[3]=a.w;
                v[4]=b.x; v[5]=b.y; v[6]=b.z; v[7]=b.w;
            } else if (k < 264) {
                const float* p = &sRoleE[sRole[r] * 8 + (k - 256)];
                #pragma unroll
                for (int j = 0; j < 8; j++) v[j] = p[j];
            } else if (k < 272) {
                const float* p = &sColE[sCol[r] * 8 + (k - 264)];
                #pragma unroll
                for (int j = 0; j < 8; j++) v[j] = p[j];
            } else {
                #pragma unroll
                for (int j = 0; j < 8; j++) v[j] = 0.0f;
            }
            half8 o;
            #pragma unroll
            for (int j = 0; j < 8; j++) o[j] = (_Float16)v[j];
            *(half8*)&sA[r * 40 + kq] = o;
        }
        {
            const int n  = tid & 127;
            const int kh = (tid >> 7) * 16;
            #pragma unroll
            for (int i = 0; i < 16; i += 2) {
                const int ka = k0 + kh + i;
                const int kb = ka + 1;
                float wa = (ka < 272) ? nW1[ka * H + n] : 0.0f;
                float wb = (kb < 272) ? nW1[kb * H + n] : 0.0f;
                union { _Float16 f[2]; unsigned u; } pk;
                pk.f[0] = (_Float16)wa; pk.f[1] = (_Float16)wb;
                *(unsigned*)&sB[n * 40 + kh + i] = pk.u;
            }
        }
        __syncthreads();
        half8 af = *(const half8*)&sA[(wv * 16 + lm) * 40 + lh * 8];
        #pragma unroll
        for (int f = 0; f < 8; f++) {
            half8 bf = *(const half8*)&sB[(f * 16 + lm) * 40 + lh * 8];
            acc[f] = __builtin_amdgcn_mfma_f32_16x16x32_f16(af, bf, acc[f], 0, 0, 0);
        }
        __syncthreads();
    }

    #pragma unroll
    for (int f = 0; f < 8; f++) {
        const int col = f * 16 + lm;
        const float b1 = nb1[col];
        #pragma unroll
        for (int v = 0; v < 4; v++) {
            const int row = wv * 16 + lh * 4 + v;
            sY[row * 136 + col] = (_Float16)silu_f(acc[f][v] + b1);
        }
    }

    floatx4 acc2[8];
    #pragma unroll
    for (int f = 0; f < 8; f++) acc2[f] = (floatx4){0.f, 0.f, 0.f, 0.f};

    __syncthreads();

    for (int s2 = 0; s2 < 4; s2++) {
        {
            const int n  = tid & 127;
            const int kh = (tid >> 7) * 16;
            #pragma unroll
            for (int i = 0; i < 16; i += 2) {
                const int ka = s2 * 32 + kh + i;
                float wa = nW2[ka * H + n];
                float wb = nW2[(ka + 1) * H + n];
                union { _Float16 f[2]; unsigned u; } pk;
                pk.f[0] = (_Float16)wa; pk.f[1] = (_Float16)wb;
                *(unsigned*)&sB[n * 40 + kh + i] = pk.u;
            }
        }
        __syncthreads();
        half8 af = *(const half8*)&sY[(wv * 16 + lm) * 136 + s2 * 32 + lh * 8];
        #pragma unroll
        for (int f = 0; f < 8; f++) {
            half8 bf = *(const half8*)&sB[(f * 16 + lm) * 40 + lh * 8];
            acc2[f] = __builtin_amdgcn_mfma_f32_16x16x32_f16(af, bf, acc2[f], 0, 0, 0);
        }
        __syncthreads();
    }

    float g[8], bb[8], b2[8];
    #pragma unroll
    for (int f = 0; f < 8; f++) {
        const int col = f * 16 + lm;
        g[f]  = ln_g[col];
        bb[f] = ln_b[col];
        b2[f] = nb2[col];
    }
    #pragma unroll
    for (int v = 0; v < 4; v++) {
        const int row = n0 + wv * 16 + lh * 4 + v;
        const int rc  = row < N ? row : N - 1;
        float x[8];
        float sum = 0.0f;
        #pragma unroll
        for (int f = 0; f < 8; f++) {
            const int col = f * 16 + lm;
            x[f] = h[rc * H + col] + acc2[f][v] + b2[f];
            sum += x[f];
        }
        sum += __shfl_xor(sum, 1);
        sum += __shfl_xor(sum, 2);
        sum += __shfl_xor(sum, 4);
        sum += __shfl_xor(sum, 8);
        const float mu = sum * (1.0f / 128.0f);
        float vs = 0.0f;
        #pragma unroll
        for (int f = 0; f < 8; f++) { float dx = x[f] - mu; vs += dx * dx; }
        vs += __shfl_xor(vs, 1);
        vs += __shfl_xor(vs, 2);
        vs += __shfl_xor(vs, 4);
        vs += __shfl_xor(vs, 8);
        const float rstd = rsqrtf(vs * (1.0f / 128.0f) + LN_EPS);
        if (row < N) {
            #pragma unroll
            for (int f = 0; f < 8; f++) {
                const int col = f * 16 + lm;
                out[row * H + col] = (x[f] - mu) * rstd * g[f] + bb[f];
            }
        }
    }
}

extern "C" void kernel_launch(void* const* d_in, const int* in_sizes, int n_in,
                              void* d_out, int out_size, void* d_ws, size_t ws_size,
                              hipStream_t stream)
{
    const float* h        = (const float*)d_in[0];
    const int*   eidx     = (const int*)d_in[1];
    const int*   erel     = (const int*)d_in[2];
    const int*   ncol     = (const int*)d_in[3];
    const int*   nrole    = (const int*)d_in[4];
    const float* rel_emb  = (const float*)d_in[5];
    const float* role_emb = (const float*)d_in[6];
    const float* col_emb  = (const float*)d_in[7];
    const float* eW1      = (const float*)d_in[8];
    const float* eb1      = (const float*)d_in[9];
    const float* eW2      = (const float*)d_in[10];
    const float* eb2      = (const float*)d_in[11];
    const float* nW1      = (const float*)d_in[12];
    const float* nb1      = (const float*)d_in[13];
    const float* nW2      = (const float*)d_in[14];
    const float* nb2      = (const float*)d_in[15];
    const float* ln_g     = (const float*)d_in[16];
    const float* ln_b     = (const float*)d_in[17];

    const int N = in_sizes[0] / H;
    const int E = in_sizes[2];
    const int* esrc = eidx;
    const int* edst = eidx + E;
    const int bsz = (N + 7) / 8;

    float* agg = (float*)d_ws;                    // N*H fp32 scratch

    // Scratch carved from d_out (dead before node_mfma writes output):
    // perm[E] | cnt[N] | base[N] | cursor[N] | binfo[16] | pad | h16 | w1te | w2te
    int* perm   = (int*)d_out;
    int* cnt    = perm + E;
    int* base   = cnt + N;
    int* cursor = base + N;
    int* binfo  = cursor + N;
    size_t io = (size_t)(E + 3 * N + 16);
    io = (io + 7) & ~(size_t)7;                   // 32B-align fp16 region
    _Float16* h16  = (_Float16*)(perm + io);
    _Float16* w1te = h16 + (size_t)N * H;         // [128][320]
    _Float16* w2te = w1te + 128 * 320;            // [128][128]

    hipMemsetAsync(agg, 0, (size_t)N * H * sizeof(float), stream);
    hipMemsetAsync(cnt, 0, (size_t)N * sizeof(int), stream);

    cvt_h16<<<(N * H / 8 + 255) / 256, 256, 0, stream>>>(h, h16, N * H / 8);
    cvt_wT<<<(128 * 320 + 255) / 256, 256, 0, stream>>>(eW1, w1te, 304, 320);
    cvt_wT<<<(128 * 128 + 255) / 256, 256, 0, stream>>>(eW2, w2te, 128, 128);

    hist2_kernel<<<512, 256, 0, stream>>>(edst, E, cnt);
    scan2_kernel<<<1, 1024, 0, stream>>>(cnt, base, cursor, N);
    binfo_kernel<<<1, 64, 0, stream>>>(base, N, bsz, E, binfo);
    scatter2_kernel<<<512, 256, 0, stream>>>(edst, E, cursor, perm);

    dim3 egrid(8, 256);
    edge_mfma<<<egrid, 256, 0, stream>>>(
        h16, perm, binfo, esrc, edst, erel, ncol, nrole,
        rel_emb, role_emb, col_emb, w1te, eb1, w2te, eb2, agg);

    node_mfma<<<(N + 63) / 64, 256, 0, stream>>>(
        h, agg, ncol, nrole, role_emb, col_emb,
        nW1, nb1, nW2, nb2, ln_g, ln_b, (float*)d_out, N);
}

// Round 10
// 505.097 us; speedup vs baseline: 1.7779x; 1.7779x over previous
//
#include <hip/hip_runtime.h>

#define H 128
#define LN_EPS 1e-5f

typedef _Float16 half8 __attribute__((ext_vector_type(8)));
typedef float floatx4 __attribute__((ext_vector_type(4)));

__device__ __forceinline__ float silu_f(float x) { return x / (1.0f + __expf(-x)); }

// ---------------------------------------------------------------------------
// fp32 -> fp16 converters (one-time per launch)
// ---------------------------------------------------------------------------
__global__ void cvt_h16(const float* __restrict__ src, _Float16* __restrict__ dst,
                        int total8)
{
    int i = blockIdx.x * blockDim.x + threadIdx.x;
    if (i >= total8) return;
    const float4* p = (const float4*)(src + i * 8);
    float4 a = p[0], b = p[1];
    half8 o;
    o[0] = (_Float16)a.x; o[1] = (_Float16)a.y; o[2] = (_Float16)a.z; o[3] = (_Float16)a.w;
    o[4] = (_Float16)b.x; o[5] = (_Float16)b.y; o[6] = (_Float16)b.z; o[7] = (_Float16)b.w;
    *(half8*)(dst + i * 8) = o;
}

// W [K][128] fp32 -> fragment-order fp16 table:
// WF[((s*8+f)*64 + lane)*8 + j] = W[(s*32+(lane>>4)*8+j)*128 + f*16+(lane&15)]
// so a step-slab (8 KB) is contiguous and a B-fragment read is lane-consecutive.
__global__ void cvt_wfrag(const float* __restrict__ W, _Float16* __restrict__ WF,
                          int K, int total)
{
    int i = blockIdx.x * blockDim.x + threadIdx.x;
    if (i >= total) return;
    int j    = i & 7;
    int lane = (i >> 3) & 63;
    int f    = (i >> 9) & 7;
    int s    = i >> 12;
    int col  = f * 16 + (lane & 15);
    int k    = s * 32 + (lane >> 4) * 8 + j;
    WF[i] = (k < K) ? (_Float16)W[k * H + col] : (_Float16)0.0f;
}

// ---------------------------------------------------------------------------
// Full counting sort by dst (N bins).
// ---------------------------------------------------------------------------
__global__ void hist2_kernel(const int* __restrict__ edst, int E,
                             int* __restrict__ cnt)
{
    for (int e = blockIdx.x * blockDim.x + threadIdx.x; e < E;
         e += gridDim.x * blockDim.x)
        atomicAdd(&cnt[edst[e]], 1);
}

__global__ void __launch_bounds__(1024)
scan2_kernel(const int* __restrict__ cnt, int* __restrict__ base,
             int* __restrict__ cursor, int N)
{
    __shared__ int part[1024];
    const int chunk = (N + 1023) >> 10;
    const int lo = threadIdx.x * chunk;
    const int hi = min(lo + chunk, N);
    int s = 0;
    for (int i = lo; i < hi; i++) s += cnt[i];
    part[threadIdx.x] = s;
    __syncthreads();
    if (threadIdx.x == 0) {
        int r = 0;
        for (int i = 0; i < 1024; i++) { int c = part[i]; part[i] = r; r += c; }
    }
    __syncthreads();
    int run = part[threadIdx.x];
    for (int i = lo; i < hi; i++) {
        base[i] = run; cursor[i] = run;
        run += cnt[i];
    }
}

__global__ void binfo_kernel(const int* __restrict__ base, int N, int bsz, int E,
                             int* __restrict__ binfo)
{
    int b = threadIdx.x;
    if (b < 8) {
        int lo = min(b * bsz, N);
        int hi = min((b + 1) * bsz, N);
        int blo = (lo >= N) ? E : base[lo];
        int bhi = (hi >= N) ? E : base[hi];
        binfo[8 + b] = blo;
        binfo[b]     = bhi - blo;
    }
}

__global__ void scatter2_kernel(const int* __restrict__ edst, int E,
                                int* __restrict__ cursor, int* __restrict__ perm)
{
    for (int e = blockIdx.x * blockDim.x + threadIdx.x; e < E;
         e += gridDim.x * blockDim.x) {
        int p = atomicAdd(&cursor[edst[e]], 1);
        perm[p] = e;
    }
}

// ---------------------------------------------------------------------------
// Edge kernel: 64-edge tiles of dst-sorted edges.
//  - A-fragments: 8 direct 16B global loads/lane into registers (no LDS RT)
//  - emb tail (k 256..319): small LDS tile
//  - B: fragment-order slabs staged cooperatively into LDS, double-buffered,
//    one barrier per K-step (4x dedupe vs per-wave global streaming)
//  - epilogue: 2-pass fp32 M overlay + run-length reduction over sorted dsts
// ---------------------------------------------------------------------------
__global__ void __launch_bounds__(256, 3)
edge_mfma(const _Float16* __restrict__ h16,
          const int* __restrict__ perm, const int* __restrict__ binfo,
          const int* __restrict__ esrc, const int* __restrict__ edst,
          const int* __restrict__ erel, const int* __restrict__ ncol,
          const int* __restrict__ nrole,
          const float* __restrict__ rel_emb, const float* __restrict__ role_emb,
          const float* __restrict__ col_emb,
          const _Float16* __restrict__ w1f,   // [10][8][64][8] fragment-order
          const float* __restrict__ eb1,
          const _Float16* __restrict__ w2f,   // [4][8][64][8]
          const float* __restrict__ eb2,
          float* __restrict__ agg)
{
    // uRegion overlays: { sB dbuf 2x8KB | sEmb 9KB }  /  { M [32][132] fp32 17KB }
    __shared__ __align__(16) unsigned char uRegion[2 * 8192 + 64 * 72 * 2];
    __shared__ __align__(16) _Float16 sY[64 * 136];
    __shared__ int sSrc[64], sDst[64], sRel[64], sRS[64], sRD[64], sCS[64], sCD[64];
    __shared__ float sRelE[128], sRoleE[48], sColE[24];

    _Float16* sB   = (_Float16*)uRegion;               // 2 slabs x 4096 halfs
    _Float16* sEmb = (_Float16*)(uRegion + 16384);     // [64][72]
    float*    M    = (float*)uRegion;                  // [32][132] epilogue

    const int tid  = threadIdx.x;
    const int lane = tid & 63;
    const int wv   = tid >> 6;
    const int lm   = lane & 15;
    const int lh   = lane >> 4;

    if (tid < 128) sRelE[tid] = rel_emb[tid];
    if (tid < 48)  sRoleE[tid] = role_emb[tid];
    if (tid < 24)  sColE[tid] = col_emb[tid];

    const int bucket = blockIdx.x;
    const int bcount = binfo[bucket];
    const int bbase  = binfo[8 + bucket];

    const int arow = wv * 16 + lm;       // edge row of this lane's A-fragment
    const int col0 = lm;                 // C col base = f*16+lm

    float bias1[8], bias2[8];
    #pragma unroll
    for (int f = 0; f < 8; f++) { bias1[f] = eb1[f * 16 + lm]; bias2[f] = eb2[f * 16 + lm]; }

    for (int t = blockIdx.y; t * 64 < bcount; t += gridDim.y)
    {
        __syncthreads();   // previous tile fully consumed (M, sDst)

        if (tid < 64) {
            int idx   = t * 64 + tid;
            int valid = idx < bcount;
            int e = valid ? perm[bbase + idx] : perm[bbase];
            int s = esrc[e], d = edst[e], r = erel[e];
            sSrc[tid] = s; sRel[tid] = r;
            sRS[tid]  = nrole[s]; sRD[tid] = nrole[d];
            sCS[tid]  = ncol[s];  sCD[tid] = ncol[d];
            sDst[tid] = valid ? d : -1;
        }
        __syncthreads();

        // ---- A-fragments: 8 independent global loads into registers ----
        half8 afr[8];
        {
            const int asrc = sSrc[arow];
            int adst = sDst[arow]; if (adst < 0) adst = asrc;
            const _Float16* sp = &h16[asrc * H + lh * 8];
            const _Float16* dp = &h16[adst * H + lh * 8];
            #pragma unroll
            for (int s = 0; s < 4; s++) afr[s]     = *(const half8*)(sp + s * 32);
            #pragma unroll
            for (int s = 0; s < 4; s++) afr[4 + s] = *(const half8*)(dp + s * 32);
        }

        // ---- emb tail -> sEmb [64][72]; B slab 0 -> sB[0] ----
        {
            const int ae = tid >> 2;
            const int q  = tid & 3;
            half8 e0, e1;
            if (q == 0) {
                const float* p = &sRelE[sRel[ae] * 16];
                #pragma unroll
                for (int j = 0; j < 8; j++) { e0[j] = (_Float16)p[j]; e1[j] = (_Float16)p[8 + j]; }
            } else if (q == 1) {
                const float* p0 = &sRoleE[sRS[ae] * 8];
                const float* p1 = &sRoleE[sRD[ae] * 8];
                #pragma unroll
                for (int j = 0; j < 8; j++) { e0[j] = (_Float16)p0[j]; e1[j] = (_Float16)p1[j]; }
            } else if (q == 2) {
                const float* p0 = &sColE[sCS[ae] * 8];
                const float* p1 = &sColE[sCD[ae] * 8];
                #pragma unroll
                for (int j = 0; j < 8; j++) { e0[j] = (_Float16)p0[j]; e1[j] = (_Float16)p1[j]; }
            } else {
                #pragma unroll
                for (int j = 0; j < 8; j++) { e0[j] = (_Float16)0.0f; e1[j] = (_Float16)0.0f; }
            }
            _Float16* w = &sEmb[ae * 72 + q * 16];
            *(half8*)(w)     = e0;
            *(half8*)(w + 8) = e1;

            const _Float16* bsrc = w1f + tid * 16;     // slab 0
            half8 b0 = *(const half8*)(bsrc);
            half8 b1 = *(const half8*)(bsrc + 8);
            _Float16* bdst = &sB[tid * 16];
            *(half8*)(bdst)     = b0;
            *(half8*)(bdst + 8) = b1;
        }

        floatx4 acc[8];
        #pragma unroll
        for (int f = 0; f < 8; f++) acc[f] = (floatx4){0.f, 0.f, 0.f, 0.f};

        __syncthreads();

        // ---- MLP1: 10 steps, B dbuf in LDS, 1 barrier/step ----
        #pragma unroll
        for (int s = 0; s < 10; s++) {
            const int cur = s & 1;
            half8 nb0, nb1;
            if (s < 9) {
                const _Float16* bsrc = w1f + (s + 1) * 4096 + tid * 16;
                nb0 = *(const half8*)(bsrc);
                nb1 = *(const half8*)(bsrc + 8);
            }
            half8 af;
            if (s < 8) af = afr[s];
            else       af = *(const half8*)&sEmb[arow * 72 + (s - 8) * 32 + lh * 8];
            #pragma unroll
            for (int f = 0; f < 8; f++) {
                half8 bf = *(const half8*)&sB[cur * 4096 + (f * 64 + lane) * 8];
                acc[f] = __builtin_amdgcn_mfma_f32_16x16x32_f16(af, bf, acc[f], 0, 0, 0);
            }
            if (s < 9) {
                _Float16* bdst = &sB[(cur ^ 1) * 4096 + tid * 16];
                *(half8*)(bdst)     = nb0;
                *(half8*)(bdst + 8) = nb1;
                __syncthreads();
            }
        }

        __syncthreads();   // sB[1]/sEmb reads done everywhere

        // sY = silu(acc + eb1); stage w2 slab 0 into sB[0]
        #pragma unroll
        for (int f = 0; f < 8; f++) {
            const int col = f * 16 + lm;
            #pragma unroll
            for (int v = 0; v < 4; v++) {
                const int row = wv * 16 + lh * 4 + v;
                sY[row * 136 + col] = (_Float16)silu_f(acc[f][v] + bias1[f]);
            }
        }
        {
            const _Float16* bsrc = w2f + tid * 16;
            half8 b0 = *(const half8*)(bsrc);
            half8 b1 = *(const half8*)(bsrc + 8);
            _Float16* bdst = &sB[tid * 16];
            *(half8*)(bdst)     = b0;
            *(half8*)(bdst + 8) = b1;
        }

        floatx4 acc2[8];
        #pragma unroll
        for (int f = 0; f < 8; f++) acc2[f] = (floatx4){0.f, 0.f, 0.f, 0.f};

        __syncthreads();

        // ---- MLP2: 4 steps, same dbuf ----
        #pragma unroll
        for (int s2 = 0; s2 < 4; s2++) {
            const int cur = s2 & 1;
            half8 nb0, nb1;
            if (s2 < 3) {
                const _Float16* bsrc = w2f + (s2 + 1) * 4096 + tid * 16;
                nb0 = *(const half8*)(bsrc);
                nb1 = *(const half8*)(bsrc + 8);
            }
            half8 af = *(const half8*)&sY[arow * 136 + s2 * 32 + lh * 8];
            #pragma unroll
            for (int f = 0; f < 8; f++) {
                half8 bf = *(const half8*)&sB[cur * 4096 + (f * 64 + lane) * 8];
                acc2[f] = __builtin_amdgcn_mfma_f32_16x16x32_f16(af, bf, acc2[f], 0, 0, 0);
            }
            if (s2 < 3) {
                _Float16* bdst = &sB[(cur ^ 1) * 4096 + tid * 16];
                *(half8*)(bdst)     = nb0;
                *(half8*)(bdst + 8) = nb1;
                __syncthreads();
            }
        }

        __syncthreads();   // all sB/sY reads done -> M overlay free

        // ---- epilogue: 2 passes of 32 rows; run-length reduced atomics ----
        #pragma unroll
        for (int p = 0; p < 2; p++) {
            if ((wv >> 1) == p) {
                #pragma unroll
                for (int f = 0; f < 8; f++) {
                    const int col = f * 16 + lm;
                    #pragma unroll
                    for (int v = 0; v < 4; v++) {
                        const int row = wv * 16 + lh * 4 + v;   // in [p*32, p*32+32)
                        M[(row & 31) * 132 + col] = silu_f(acc2[f][v] + bias2[f]);
                    }
                }
            }
            __syncthreads();
            {
                const int c  = tid & 127;
                const int rb = (tid >> 7) * 16;       // 0 or 16 within pass
                float a = 0.0f;
                int cur = -1;
                #pragma unroll
                for (int r = rb; r < rb + 16; r++) {
                    int d = sDst[p * 32 + r];
                    if (d != cur) {
                        if (cur >= 0) unsafeAtomicAdd(&agg[cur * H + c], a);
                        a = 0.0f; cur = d;
                    }
                    if (d >= 0) a += M[r * 132 + c];
                }
                if (cur >= 0) unsafeAtomicAdd(&agg[cur * H + c], a);
            }
            __syncthreads();
        }
    }
}

// ---------------------------------------------------------------------------
// Node kernel (fp16 MFMA): unchanged (not the bottleneck).
// ---------------------------------------------------------------------------
__global__ void __launch_bounds__(256)
node_mfma(const float* __restrict__ h, const float* __restrict__ agg,
          const int* __restrict__ ncol, const int* __restrict__ nrole,
          const float* __restrict__ role_emb, const float* __restrict__ col_emb,
          const float* __restrict__ nW1, const float* __restrict__ nb1,
          const float* __restrict__ nW2, const float* __restrict__ nb2,
          const float* __restrict__ ln_g, const float* __restrict__ ln_b,
          float* __restrict__ out, int N)
{
    __shared__ _Float16 sA[64 * 40];
    __shared__ _Float16 sB[128 * 40];
    __shared__ _Float16 sY[64 * 136];
    __shared__ int sRole[64], sCol[64];
    __shared__ float sRoleE[48], sColE[24];

    const int tid  = threadIdx.x;
    const int lane = tid & 63;
    const int wv   = tid >> 6;
    const int lm   = lane & 15;
    const int lh   = lane >> 4;
    const int n0   = blockIdx.x * 64;

    if (tid < 48) sRoleE[tid] = role_emb[tid];
    if (tid < 24) sColE[tid] = col_emb[tid];
    if (tid < 64) {
        int n = n0 + tid; if (n >= N) n = N - 1;
        sRole[tid] = nrole[n];
        sCol[tid]  = ncol[n];
    }

    floatx4 acc[8];
    #pragma unroll
    for (int f = 0; f < 8; f++) acc[f] = (floatx4){0.f, 0.f, 0.f, 0.f};

    __syncthreads();

    for (int s = 0; s < 9; s++) {
        const int k0 = s * 32;
        {
            const int r  = tid >> 2;
            const int kq = (tid & 3) * 8;
            const int k  = k0 + kq;
            int n = n0 + r; if (n >= N) n = N - 1;
            float v[8];
            if (k < 128) {
                const float4* p = (const float4*)&h[n * H + k];
                float4 a = p[0], b = p[1];
                v[0]=a.x; v[1]=a.y; v[2]=a.z; v[3]=a.w;
                v[4]=b.x; v[5]=b.y; v[6]=b.z; v[7]=b.w;
            } else if (k < 256) {
                const float4* p = (const float4*)&agg[n * H + (k - 128)];
                float4 a = p[0], b = p[1];
                v[0]=a.x; v[1]=a.y; v[2]=a.z; v[3]=a.w;
                v[4]=b.x; v[5]=b.y; v[6]=b.z; v[7]=b.w;
            } else if (k < 264) {
                const float* p = &sRoleE[sRole[r] * 8 + (k - 256)];
                #pragma unroll
                for (int j = 0; j < 8; j++) v[j] = p[j];
            } else if (k < 272) {
                const float* p = &sColE[sCol[r] * 8 + (k - 264)];
                #pragma unroll
                for (int j = 0; j < 8; j++) v[j] = p[j];
            } else {
                #pragma unroll
                for (int j = 0; j < 8; j++) v[j] = 0.0f;
            }
            half8 o;
            #pragma unroll
            for (int j = 0; j < 8; j++) o[j] = (_Float16)v[j];
            *(half8*)&sA[r * 40 + kq] = o;
        }
        {
            const int n  = tid & 127;
            const int kh = (tid >> 7) * 16;
            #pragma unroll
            for (int i = 0; i < 16; i += 2) {
                const int ka = k0 + kh + i;
                const int kb = ka + 1;
                float wa = (ka < 272) ? nW1[ka * H + n] : 0.0f;
                float wb = (kb < 272) ? nW1[kb * H + n] : 0.0f;
                union { _Float16 f[2]; unsigned u; } pk;
                pk.f[0] = (_Float16)wa; pk.f[1] = (_Float16)wb;
                *(unsigned*)&sB[n * 40 + kh + i] = pk.u;
            }
        }
        __syncthreads();
        half8 af = *(const half8*)&sA[(wv * 16 + lm) * 40 + lh * 8];
        #pragma unroll
        for (int f = 0; f < 8; f++) {
            half8 bf = *(const half8*)&sB[(f * 16 + lm) * 40 + lh * 8];
            acc[f] = __builtin_amdgcn_mfma_f32_16x16x32_f16(af, bf, acc[f], 0, 0, 0);
        }
        __syncthreads();
    }

    #pragma unroll
    for (int f = 0; f < 8; f++) {
        const int col = f * 16 + lm;
        const float b1 = nb1[col];
        #pragma unroll
        for (int v = 0; v < 4; v++) {
            const int row = wv * 16 + lh * 4 + v;
            sY[row * 136 + col] = (_Float16)silu_f(acc[f][v] + b1);
        }
    }

    floatx4 acc2[8];
    #pragma unroll
    for (int f = 0; f < 8; f++) acc2[f] = (floatx4){0.f, 0.f, 0.f, 0.f};

    __syncthreads();

    for (int s2 = 0; s2 < 4; s2++) {
        {
            const int n  = tid & 127;
            const int kh = (tid >> 7) * 16;
            #pragma unroll
            for (int i = 0; i < 16; i += 2) {
                const int ka = s2 * 32 + kh + i;
                float wa = nW2[ka * H + n];
                float wb = nW2[(ka + 1) * H + n];
                union { _Float16 f[2]; unsigned u; } pk;
                pk.f[0] = (_Float16)wa; pk.f[1] = (_Float16)wb;
                *(unsigned*)&sB[n * 40 + kh + i] = pk.u;
            }
        }
        __syncthreads();
        half8 af = *(const half8*)&sY[(wv * 16 + lm) * 136 + s2 * 32 + lh * 8];
        #pragma unroll
        for (int f = 0; f < 8; f++) {
            half8 bf = *(const half8*)&sB[(f * 16 + lm) * 40 + lh * 8];
            acc2[f] = __builtin_amdgcn_mfma_f32_16x16x32_f16(af, bf, acc2[f], 0, 0, 0);
        }
        __syncthreads();
    }

    float g[8], bb[8], b2[8];
    #pragma unroll
    for (int f = 0; f < 8; f++) {
        const int col = f * 16 + lm;
        g[f]  = ln_g[col];
        bb[f] = ln_b[col];
        b2[f] = nb2[col];
    }
    #pragma unroll
    for (int v = 0; v < 4; v++) {
        const int row = n0 + wv * 16 + lh * 4 + v;
        const int rc  = row < N ? row : N - 1;
        float x[8];
        float sum = 0.0f;
        #pragma unroll
        for (int f = 0; f < 8; f++) {
            const int col = f * 16 + lm;
            x[f] = h[rc * H + col] + acc2[f][v] + b2[f];
            sum += x[f];
        }
        sum += __shfl_xor(sum, 1);
        sum += __shfl_xor(sum, 2);
        sum += __shfl_xor(sum, 4);
        sum += __shfl_xor(sum, 8);
        const float mu = sum * (1.0f / 128.0f);
        float vs = 0.0f;
        #pragma unroll
        for (int f = 0; f < 8; f++) { float dx = x[f] - mu; vs += dx * dx; }
        vs += __shfl_xor(vs, 1);
        vs += __shfl_xor(vs, 2);
        vs += __shfl_xor(vs, 4);
        vs += __shfl_xor(vs, 8);
        const float rstd = rsqrtf(vs * (1.0f / 128.0f) + LN_EPS);
        if (row < N) {
            #pragma unroll
            for (int f = 0; f < 8; f++) {
                const int col = f * 16 + lm;
                out[row * H + col] = (x[f] - mu) * rstd * g[f] + bb[f];
            }
        }
    }
}

extern "C" void kernel_launch(void* const* d_in, const int* in_sizes, int n_in,
                              void* d_out, int out_size, void* d_ws, size_t ws_size,
                              hipStream_t stream)
{
    const float* h        = (const float*)d_in[0];
    const int*   eidx     = (const int*)d_in[1];
    const int*   erel     = (const int*)d_in[2];
    const int*   ncol     = (const int*)d_in[3];
    const int*   nrole    = (const int*)d_in[4];
    const float* rel_emb  = (const float*)d_in[5];
    const float* role_emb = (const float*)d_in[6];
    const float* col_emb  = (const float*)d_in[7];
    const float* eW1      = (const float*)d_in[8];
    const float* eb1      = (const float*)d_in[9];
    const float* eW2      = (const float*)d_in[10];
    const float* eb2      = (const float*)d_in[11];
    const float* nW1      = (const float*)d_in[12];
    const float* nb1      = (const float*)d_in[13];
    const float* nW2      = (const float*)d_in[14];
    const float* nb2      = (const float*)d_in[15];
    const float* ln_g     = (const float*)d_in[16];
    const float* ln_b     = (const float*)d_in[17];

    const int N = in_sizes[0] / H;
    const int E = in_sizes[2];
    const int* esrc = eidx;
    const int* edst = eidx + E;
    const int bsz = (N + 7) / 8;

    float* agg = (float*)d_ws;                    // N*H fp32 scratch

    // Scratch carved from d_out (dead before node_mfma writes output):
    // perm[E] | cnt[N] | base[N] | cursor[N] | binfo[16] | pad | h16 | w1f | w2f
    int* perm   = (int*)d_out;
    int* cnt    = perm + E;
    int* base   = cnt + N;
    int* cursor = base + N;
    int* binfo  = cursor + N;
    size_t io = (size_t)(E + 3 * N + 16);
    io = (io + 7) & ~(size_t)7;                   // 32B-align fp16 region
    _Float16* h16 = (_Float16*)(perm + io);
    _Float16* w1f = h16 + (size_t)N * H;          // 10*4096 halfs
    _Float16* w2f = w1f + 10 * 4096;              // 4*4096 halfs

    hipMemsetAsync(agg, 0, (size_t)N * H * sizeof(float), stream);
    hipMemsetAsync(cnt, 0, (size_t)N * sizeof(int), stream);

    cvt_h16<<<(N * H / 8 + 255) / 256, 256, 0, stream>>>(h, h16, N * H / 8);
    cvt_wfrag<<<(10 * 4096 + 255) / 256, 256, 0, stream>>>(eW1, w1f, 304, 10 * 4096);
    cvt_wfrag<<<(4 * 4096 + 255) / 256, 256, 0, stream>>>(eW2, w2f, 128, 4 * 4096);

    hist2_kernel<<<512, 256, 0, stream>>>(edst, E, cnt);
    scan2_kernel<<<1, 1024, 0, stream>>>(cnt, base, cursor, N);
    binfo_kernel<<<1, 64, 0, stream>>>(base, N, bsz, E, binfo);
    scatter2_kernel<<<512, 256, 0, stream>>>(edst, E, cursor, perm);

    dim3 egrid(8, 256);
    edge_mfma<<<egrid, 256, 0, stream>>>(
        h16, perm, binfo, esrc, edst, erel, ncol, nrole,
        rel_emb, role_emb, col_emb, w1f, eb1, w2f, eb2, agg);

    node_mfma<<<(N + 63) / 64, 256, 0, stream>>>(
        h, agg, ncol, nrole, role_emb, col_emb,
        nW1, nb1, nW2, nb2, ln_g, ln_b, (float*)d_out, N);
}